// Round 5
// baseline (2119.851 us; speedup 1.0000x reference)
//
#include <hip/hip_runtime.h>

// psRNN round 5: round-3/4 compute structure + round-2's PROVEN agent-scope
// (LLC) flag fabric. sc0-flag variants (r3/r4) hung at infra level twice;
// agent-scope flags ran end-to-end (r1/r2). Everything else kept:
//  - 8 replicas (one per XCD via HW_REG_XCC_ID) x 32 blocks x 4 waves
//  - replica owns batches [8r,8r+8) (MFMA M=16, rows 8-15 mirror rows 0-7)
//  - block owns 64 neurons; wave w combines neurons [n0+16w,+16) and computes
//    K-slice [512w,+512) for all 4 block tiles (split-K=4, LDS reduce, pad 18)
//  - u-projection register-resident (no red_u LDS), ONE __syncthreads/step
//  - per-WAVE producer flags, publish after wave-local vmcnt(0)
//  - state triple-buffered, sc0 loads/stores (XCD L2 resident, proven in r2)
//  - x prefetch after flag publish (off the serial chain)
//  - s_sleep(1) backoff in the poll

typedef _Float16 half_t;
typedef _Float16 half8 __attribute__((ext_vector_type(8)));
typedef float f32x4 __attribute__((ext_vector_type(4)));

#define T_STEPS 512
#define NINP 64
#define NHID 2048
#define NOUT 64
#define ST_BUF 131072   // halfs per state buffer (8 reps x 16384)
#define ST_REP 16384    // halfs per replica slice (64cg x 4kg x 8m x 8j)

#define MFMA16(A, B, C) __builtin_amdgcn_mfma_f32_16x16x32_f16(A, B, C, 0, 0, 0)

// ws layout:
//   [0, 4096)        : flags  uint[8][128]  ([rep][slot*4+wave], monotonic)
//   [4096, 4128)     : roster uint[8]
//   [8192, 8192+768K): St     half[3][8][64][4][8][8]  (buf, rep, cg, kg, m, j)

__device__ __forceinline__ half8 cvt8(float4 lo, float4 hi) {
  half8 h;
  h[0] = (half_t)lo.x; h[1] = (half_t)lo.y; h[2] = (half_t)lo.z; h[3] = (half_t)lo.w;
  h[4] = (half_t)hi.x; h[5] = (half_t)hi.y; h[6] = (half_t)hi.z; h[7] = (half_t)hi.w;
  return h;
}

__global__ void psrnn_init_kernel(unsigned* flags, unsigned* roster, uint4* st) {
  int g = blockIdx.x * blockDim.x + threadIdx.x;  // 16384 threads
  uint4 v; v.x = 0x3C003C00u; v.y = 0x3C003C00u; v.z = 0x3C003C00u; v.w = 0x3C003C00u;
  st[g] = v;                                      // buffer 0 := fp16 1.0 (256KB)
  if (g < 1024) flags[g] = 0;
  else if (g < 1032) roster[g - 1024] = 0;
}

__global__ __launch_bounds__(256, 1) void psrnn_main_kernel(
    const float* __restrict__ x,      // [512][64][64]
    const float* __restrict__ Wi_w,   // [2048][64]
    const float* __restrict__ Wi_b,   // [2048]
    const float* __restrict__ Wh_w,   // [2048][2048]
    const float* __restrict__ Av,     // [2048]
    const float* __restrict__ Om,     // [2048]
    unsigned* __restrict__ flags,
    unsigned* __restrict__ roster,
    half_t* __restrict__ St)
{
  __shared__ float red_y[2][4][4][16][18];  // [par][kw][nt][m][n] pad18 => 2-way (free)
  __shared__ unsigned slot_sh;

  const int tid  = threadIdx.x;
  const int w    = tid >> 6;     // wave id = combine tile = K-slice id
  const int lane = tid & 63;
  const int lm   = lane & 15;
  const int kg   = lane >> 4;

  unsigned xcd;
  asm volatile("s_getreg_b32 %0, hwreg(HW_REG_XCC_ID)" : "=s"(xcd));
  const int rep = (int)(xcd & 7u);
  if (tid == 0) slot_sh = atomicAdd(&roster[rep], 1u) & 31u;
  __syncthreads();
  const int slot = (int)slot_sh;
  const int n0   = slot * 64;
  const int b0   = rep * 8;

  // Wh slice -> B-frags: breg[nt][c] = neurons n0+16nt+lm, K = 512w + 32c + 8kg..
  half8 breg[4][16];
#pragma unroll
  for (int nt = 0; nt < 4; ++nt) {
#pragma unroll
    for (int c = 0; c < 16; ++c) {
      const float* p = Wh_w + (size_t)(n0 + nt * 16 + lm) * NHID + (w * 512 + c * 32 + kg * 8);
      breg[nt][c] = cvt8(*(const float4*)p, *(const float4*)(p + 4));
    }
  }
  // Wi slice for this wave's combine tile (nt == w)
  half8 wiReg[2];
#pragma unroll
  for (int c2 = 0; c2 < 2; ++c2) {
    const float* p = Wi_w + (size_t)(n0 + w * 16 + lm) * NINP + (c2 * 32 + kg * 8);
    wiReg[c2] = cvt8(*(const float4*)p, *(const float4*)(p + 4));
  }

  // per-lane combine constants: neuron ng = n0 + 16w + lm, batches kg*4+r (real if kg<2)
  const int ng = n0 + w * 16 + lm;
  const float cAv = Av[ng], cOmv = Om[ng], cBv = Wi_b[ng];
  const int offh = (ng >> 5) * 256 + ((ng >> 3) & 3) * 64 + kg * 32 + (ng & 7);
  float s[4] = {1.f, 1.f, 1.f, 1.f};  // fp32 master state for the cos path

  unsigned* const pollp = flags + rep * 128 + w * 32 + (lane & 31);
  unsigned* const myf   = flags + rep * 128 + slot * 4 + w;

  // x A-frag prefetch for t=0 (rows = batch b0 + (lm&7), mirrored)
  float4 xr0, xr1, xr2, xr3;
  {
    const float* xp = x + (size_t)(b0 + (lm & 7)) * NINP;
    xr0 = *(const float4*)(xp + kg * 8);
    xr1 = *(const float4*)(xp + kg * 8 + 4);
    xr2 = *(const float4*)(xp + 32 + kg * 8);
    xr3 = *(const float4*)(xp + 32 + kg * 8 + 4);
  }

  int bR = 0;  // t % 3
  for (int t = 0; t < T_STEPS; ++t) {
    const int bW = (bR == 2) ? 0 : bR + 1;
    const half_t* stc = St + (size_t)bR * ST_BUF + rep * ST_REP;
    half_t* stn       = St + (size_t)bW * ST_BUF + rep * ST_REP;
    const int par = t & 1;

    // ---- phase A (state-independent): u-tile, result stays in registers
    f32x4 au = {0.f, 0.f, 0.f, 0.f};
    {
      half8 xa0 = cvt8(xr0, xr1);
      half8 xa1 = cvt8(xr2, xr3);
      au = MFMA16(xa0, wiReg[0], au);
      au = MFMA16(xa1, wiReg[1], au);
    }

    // ---- phase B: wait for THIS wave's 32 producer waves (slots 8w..8w+8)
    //      at AGENT scope (LLC) — the mechanism proven in rounds 1-2.
    {
      const unsigned tgt = (unsigned)t;
      unsigned v = __hip_atomic_load(pollp, __ATOMIC_RELAXED, __HIP_MEMORY_SCOPE_AGENT);
      while (!__all((int)(v >= tgt))) {
        __builtin_amdgcn_s_sleep(1);
        v = __hip_atomic_load(pollp, __ATOMIC_RELAXED, __HIP_MEMORY_SCOPE_AGENT);
      }
    }

    // ---- phase C: state A-frags from XCD L2 (16 cg chunks of this wave's K slice)
    const half_t* p0 = stc + w * 4096 + kg * 64 + (lm & 7) * 8;
    const half_t* p1 = p0 + 2048;
    float4 Ar[16];
    asm volatile(
        "global_load_dwordx4 %0, %16, off sc0\n\t"
        "global_load_dwordx4 %1, %16, off offset:512 sc0\n\t"
        "global_load_dwordx4 %2, %16, off offset:1024 sc0\n\t"
        "global_load_dwordx4 %3, %16, off offset:1536 sc0\n\t"
        "global_load_dwordx4 %4, %16, off offset:2048 sc0\n\t"
        "global_load_dwordx4 %5, %16, off offset:2560 sc0\n\t"
        "global_load_dwordx4 %6, %16, off offset:3072 sc0\n\t"
        "global_load_dwordx4 %7, %16, off offset:3584 sc0\n\t"
        "global_load_dwordx4 %8, %17, off sc0\n\t"
        "global_load_dwordx4 %9, %17, off offset:512 sc0\n\t"
        "global_load_dwordx4 %10, %17, off offset:1024 sc0\n\t"
        "global_load_dwordx4 %11, %17, off offset:1536 sc0\n\t"
        "global_load_dwordx4 %12, %17, off offset:2048 sc0\n\t"
        "global_load_dwordx4 %13, %17, off offset:2560 sc0\n\t"
        "global_load_dwordx4 %14, %17, off offset:3072 sc0\n\t"
        "global_load_dwordx4 %15, %17, off offset:3584 sc0\n\t"
        "s_waitcnt vmcnt(0)"
        : "=&v"(Ar[0]), "=&v"(Ar[1]), "=&v"(Ar[2]), "=&v"(Ar[3]),
          "=&v"(Ar[4]), "=&v"(Ar[5]), "=&v"(Ar[6]), "=&v"(Ar[7]),
          "=&v"(Ar[8]), "=&v"(Ar[9]), "=&v"(Ar[10]), "=&v"(Ar[11]),
          "=&v"(Ar[12]), "=&v"(Ar[13]), "=&v"(Ar[14]), "=&v"(Ar[15])
        : "v"(p0), "v"(p1)
        : "memory");

    // ---- phase D: split-K partials for all 4 block tiles
    f32x4 a0 = {0.f,0.f,0.f,0.f}, a1 = {0.f,0.f,0.f,0.f};
    f32x4 a2 = {0.f,0.f,0.f,0.f}, a3 = {0.f,0.f,0.f,0.f};
#pragma unroll
    for (int c = 0; c < 16; ++c) {
      half8 a = __builtin_bit_cast(half8, Ar[c]);
      a0 = MFMA16(a, breg[0][c], a0);
      a1 = MFMA16(a, breg[1][c], a1);
      a2 = MFMA16(a, breg[2][c], a2);
      a3 = MFMA16(a, breg[3][c], a3);
    }
#pragma unroll
    for (int r = 0; r < 4; ++r) {
      red_y[par][w][0][kg * 4 + r][lm] = a0[r];
      red_y[par][w][1][kg * 4 + r][lm] = a1[r];
      red_y[par][w][2][kg * 4 + r][lm] = a2[r];
      red_y[par][w][3][kg * 4 + r][lm] = a3[r];
    }
    __syncthreads();  // the only barrier per step

    // ---- phase E: wave-local combine (tile nt == w), publish state + flag
#pragma unroll
    for (int r = 0; r < 4; ++r) {
      const int m = kg * 4 + r;
      const float yy = red_y[par][0][w][m][lm] + red_y[par][1][w][m][lm] +
                       red_y[par][2][w][m][lm] + red_y[par][3][w][m][lm];
      const float sn = cAv * __cosf(cOmv * s[r] + au[r] + cBv) + yy;
      s[r] = sn;
      if (kg < 2) {
        unsigned hv = (unsigned)__builtin_bit_cast(unsigned short, (half_t)sn);
        const half_t* sp = stn + offh + r * 8;
        asm volatile("global_store_short %0, %1, off sc0" :: "v"(sp), "v"(hv) : "memory");
      }
    }
    asm volatile("s_waitcnt vmcnt(0)" ::: "memory");  // wave's state stores in L2
    if (lane == 0)
      __hip_atomic_store(myf, (unsigned)(t + 1), __ATOMIC_RELAXED, __HIP_MEMORY_SCOPE_AGENT);

    // ---- phase F: x prefetch for t+1 (after publish -> off the serial chain)
    if (t + 1 < T_STEPS) {
      const float* xp = x + ((size_t)(t + 1) * 64 + b0 + (lm & 7)) * NINP;
      xr0 = *(const float4*)(xp + kg * 8);
      xr1 = *(const float4*)(xp + kg * 8 + 4);
      xr2 = *(const float4*)(xp + 32 + kg * 8);
      xr3 = *(const float4*)(xp + 32 + kg * 8 + 4);
    }
    bR = bW;
  }
}

__global__ __launch_bounds__(256) void psrnn_readout_kernel(
    const float* __restrict__ Wr_w,   // [64][2048]
    const float* __restrict__ Wr_b,   // [64]
    const half_t* __restrict__ St,    // final state buffer (buf 2), frag layout
    float* __restrict__ out)          // [64][64]
{
  const int tid  = threadIdx.x;
  const int v    = tid >> 6;   // wave = out-neuron tile
  const int lane = tid & 63;
  const int lm   = lane & 15;
  const int kg   = lane >> 4;
  const int rep  = blockIdx.x; // 8 blocks, one per replica

  const half_t* sb = St + (size_t)rep * ST_REP;
  f32x4 acc = {0.f, 0.f, 0.f, 0.f};
  for (int cg = 0; cg < 64; ++cg) {
    half8 a = *(const half8*)(sb + (size_t)cg * 256 + kg * 64 + (lm & 7) * 8);
    const float* p = Wr_w + (size_t)(v * 16 + lm) * NHID + cg * 32 + kg * 8;
    half8 b = cvt8(*(const float4*)p, *(const float4*)(p + 4));
    acc = MFMA16(a, b, acc);
  }
  if (kg < 2) {
#pragma unroll
    for (int r = 0; r < 4; ++r) {
      const int b = rep * 8 + kg * 4 + r;
      out[b * NOUT + v * 16 + lm] = acc[r] + Wr_b[v * 16 + lm];
    }
  }
}

extern "C" void kernel_launch(void* const* d_in, const int* in_sizes, int n_in,
                              void* d_out, int out_size, void* d_ws, size_t ws_size,
                              hipStream_t stream) {
  const float* x    = (const float*)d_in[0];
  const float* Wi_w = (const float*)d_in[1];
  const float* Wi_b = (const float*)d_in[2];
  const float* Wh_w = (const float*)d_in[3];
  const float* Av   = (const float*)d_in[4];
  const float* Om   = (const float*)d_in[5];
  const float* Wr_w = (const float*)d_in[6];
  const float* Wr_b = (const float*)d_in[7];

  unsigned* flags  = (unsigned*)d_ws;
  unsigned* roster = (unsigned*)((char*)d_ws + 4096);
  half_t*   St     = (half_t*)((char*)d_ws + 8192);

  psrnn_init_kernel<<<64, 256, 0, stream>>>(flags, roster, (uint4*)St);
  psrnn_main_kernel<<<256, 256, 0, stream>>>(x, Wi_w, Wi_b, Wh_w, Av, Om, flags, roster, St);
  // final state (t=511 writes buffer (511+1)%3 = 2)
  psrnn_readout_kernel<<<8, 256, 0, stream>>>(Wr_w, Wr_b, St + 2 * ST_BUF, (float*)d_out);
}

// Round 6
// 1279.856 us; speedup vs baseline: 1.6563x; 1.6563x over previous
//
#include <hip/hip_runtime.h>

// psRNN round 6: TWO timesteps per sync via W^2 reassociation.
//   s_{t+1} = c_t + W s_t,  c_t = A*cos(omega*s_t + u_t)
//   s_{t+2} = c_{t+1} + W c_t + W^2 s_t
// Owners publish BOTH s_t[O] and c_t[O] (c is elementwise-local at publish
// time), so one sync feeds two steps. 256 rounds instead of 512 syncs.
//
// Topology: 4 replicas x 64 blocks x 4 waves. Replica r owns batches
// [16r,16r+16) (MFMA M=16, all real). Block owns 32 neurons; per wave:
// B-frags of W (2ntx16c) + W^2 (2ntx16c) = 256 VGPR. Wave w covers K-slice
// [512w,+512): per round 96 MFMA (y1=W*s for s_{t+1}[O]; y23=W*c+W^2*s).
// Split-K=4 partials reduced in LDS (pad 18), ONE barrier per round.
// u = Wi x_t + b computed in-loop by wave specialization (2 MFMA/wave).
// Sync fabric (PROVEN): per-wave agent-scope flags (tight spin, no sleep);
// state/c published with sc1 (agent/LLC write-through) asm stores after
// wave-local vmcnt(0). Triple-buffered (s,c): write@k hits buf (k+1)%3,
// conflicting reads are @k-2; 2-hop flag transitivity + the round barrier
// make that safe (see r3 proof, now over rounds).
// W^2 precomputed on-device: transpose kernel (W -> WT f16) + f16 MFMA GEMM.

typedef _Float16 half_t;
typedef _Float16 half8 __attribute__((ext_vector_type(8)));
typedef float f32x4 __attribute__((ext_vector_type(4)));

#define NHID 2048
#define NOUT 64
#define ST_UNIT 65536   // halfs per (buf,rep): s [0,32768) + c [32768,65536)
#define N_ROUNDS 256

#define MFMA16(A, B, C) __builtin_amdgcn_mfma_f32_16x16x32_f16(A, B, C, 0, 0, 0)

// ws layout (bytes):
//   [0, 4096)              : flags uint[4][256]  ([rep][slot*4+wave])
//   [4096, 4096+1.5M)      : St half[3 buf][4 rep][ST_UNIT]
//   [2M, 2M+8M)            : W2f16 half[2048][2048]
//   [10M+2M=10485760, +8M) : WT16  half[2048][2048]  (W transposed, f16)

__device__ __forceinline__ half8 cvt8(float4 lo, float4 hi) {
  half8 h;
  h[0] = (half_t)lo.x; h[1] = (half_t)lo.y; h[2] = (half_t)lo.z; h[3] = (half_t)lo.w;
  h[4] = (half_t)hi.x; h[5] = (half_t)hi.y; h[6] = (half_t)hi.z; h[7] = (half_t)hi.w;
  return h;
}

__global__ void psrnn_init_kernel(unsigned* flags, uint4* st) {
  int g = blockIdx.x * blockDim.x + threadIdx.x;  // 16384 threads
  // s of buffer 0, all 4 reps := fp16 1.0 (4 x 64KB)
  uint4 v; v.x = 0x3C003C00u; v.y = 0x3C003C00u; v.z = 0x3C003C00u; v.w = 0x3C003C00u;
  const int rep = g >> 12, local = g & 4095;
  st[rep * (ST_UNIT / 8) + local] = v;
  if (g < 1024) flags[g] = 0;
}

// W (fp32 row-major) -> WT16 (f16, transposed, row-major)
__global__ __launch_bounds__(256) void psrnn_transpose_kernel(
    const float* __restrict__ Wh, half_t* __restrict__ WT16) {
  __shared__ float tile[64][65];
  const int bi = blockIdx.x & 31, bj = blockIdx.x >> 5;
  const int rs = threadIdx.x >> 6, c = threadIdx.x & 63;
#pragma unroll
  for (int i = 0; i < 16; ++i) {
    const int row = rs * 16 + i;
    tile[row][c] = Wh[(size_t)(bi * 64 + row) * NHID + bj * 64 + c];
  }
  __syncthreads();
#pragma unroll
  for (int i = 0; i < 16; ++i) {
    const int row = rs * 16 + i;
    WT16[(size_t)(bj * 64 + row) * NHID + bi * 64 + c] = (half_t)tile[c][row];
  }
}

// W2f16 = f16( f16(W) @ f16(W) ),  W2[i][j] = sum_k W[i][k] * WT16[j][k]
__global__ __launch_bounds__(256) void psrnn_w2_kernel(
    const float* __restrict__ Wh, const half_t* __restrict__ WT16,
    half_t* __restrict__ W2) {
  const int bi = blockIdx.x & 31, bj = blockIdx.x >> 5;
  const int w = threadIdx.x >> 6, lane = threadIdx.x & 63;
  const int lm = lane & 15, kg = lane >> 4;
  const int rowA = bi * 64 + w * 16 + lm;
  f32x4 acc[4];
#pragma unroll
  for (int bt = 0; bt < 4; ++bt) acc[bt] = (f32x4){0.f, 0.f, 0.f, 0.f};
  for (int c = 0; c < 64; ++c) {
    const float* pa = Wh + (size_t)rowA * NHID + c * 32 + kg * 8;
    half8 a = cvt8(*(const float4*)pa, *(const float4*)(pa + 4));
#pragma unroll
    for (int bt = 0; bt < 4; ++bt) {
      half8 b = *(const half8*)(WT16 + (size_t)(bj * 64 + bt * 16 + lm) * NHID + c * 32 + kg * 8);
      acc[bt] = MFMA16(a, b, acc[bt]);
    }
  }
#pragma unroll
  for (int bt = 0; bt < 4; ++bt)
#pragma unroll
    for (int r = 0; r < 4; ++r)
      W2[(size_t)(bi * 64 + w * 16 + kg * 4 + r) * NHID + bj * 64 + bt * 16 + lm] =
          (half_t)acc[bt][r];
}

__global__ __launch_bounds__(256, 1) void psrnn_main_kernel(
    const float* __restrict__ x,      // [512][64][64]
    const float* __restrict__ Wi_w,   // [2048][64]
    const float* __restrict__ Wi_b,   // [2048]
    const float* __restrict__ Wh_w,   // [2048][2048]
    const float* __restrict__ Av,     // [2048]
    const float* __restrict__ Om,     // [2048]
    const half_t* __restrict__ W2,    // [2048][2048] f16
    unsigned* __restrict__ flags,
    half_t* __restrict__ St)
{
  __shared__ float ybuf[2][4][2][2][16][18];  // [par][wave][arr(y1,y23)][nt][m][n]
  __shared__ float ubuf[2][2][2][16][18];     // [par][t'][nt][m][n]

  const int tid = threadIdx.x, w = tid >> 6, lane = tid & 63;
  const int lm = lane & 15, kg = lane >> 4;
  const int rep = blockIdx.x & 3, slot = blockIdx.x >> 2;
  const int n0 = slot * 32, b0 = rep * 16;
  const int tpar = w >> 1, ntu = w & 1;  // u-duty: wave -> (timestep, nt)

  // ---- W, W2 B-frags: rows n0+16nt+lm, K = 512w + 32c + kg*8..
  half8 wb[2][16], w2b[2][16];
#pragma unroll
  for (int nt = 0; nt < 2; ++nt)
#pragma unroll
    for (int c = 0; c < 16; ++c) {
      const float* p = Wh_w + (size_t)(n0 + nt * 16 + lm) * NHID + (w * 512 + c * 32 + kg * 8);
      wb[nt][c] = cvt8(*(const float4*)p, *(const float4*)(p + 4));
      w2b[nt][c] = *(const half8*)(W2 + (size_t)(n0 + nt * 16 + lm) * NHID +
                                   (w * 512 + c * 32 + kg * 8));
    }
  // Wi B-frags for this wave's u duty (neurons n0+16ntu+..)
  half8 wi0, wi1;
  {
    const float* p = Wi_w + (size_t)(n0 + ntu * 16 + lm) * 64 + kg * 8;
    wi0 = cvt8(*(const float4*)p, *(const float4*)(p + 4));
    wi1 = cvt8(*(const float4*)(p + 32), *(const float4*)(p + 36));
  }

  // ---- combiner constants: thread owns (batch m, neurons n0+nt*16+nn)
  const int m = tid >> 4, nn = tid & 15;
  float cA2[2], cOm2[2], cB2[2];
  int off2[2];
#pragma unroll
  for (int nt = 0; nt < 2; ++nt) {
    const int ng = n0 + nt * 16 + nn;
    cA2[nt] = Av[ng]; cOm2[nt] = Om[ng]; cB2[nt] = Wi_b[ng];
    off2[nt] = ((slot * 4 + nt * 2 + (nn >> 3)) * 16 + m) * 8 + (nn & 7);
  }
  float cpr[2];  // c_prev[O] fp32 (owner-resident)

  unsigned* const pollp = flags + rep * 256 + w * 64 + lane;  // 64 producer waves
  unsigned* const myf   = flags + rep * 256 + slot * 4 + w;

  // ---- preloop: u_0 (waves 0,1), publish c_0 to buf0, flag=1
  if (w < 2) {
    const float* xp = x + (size_t)(b0 + lm) * 64;
    float4 a0 = *(const float4*)(xp + kg * 8), a1 = *(const float4*)(xp + kg * 8 + 4);
    float4 a2 = *(const float4*)(xp + 32 + kg * 8), a3 = *(const float4*)(xp + 36 + kg * 8);
    f32x4 au = {0.f, 0.f, 0.f, 0.f};
    au = MFMA16(cvt8(a0, a1), wi0, au);
    au = MFMA16(cvt8(a2, a3), wi1, au);
#pragma unroll
    for (int r = 0; r < 4; ++r) ubuf[0][0][ntu][kg * 4 + r][lm] = au[r];
  }
  __syncthreads();
  {
    half_t* w0c = St + (size_t)rep * ST_UNIT + 32768;  // buf0 c-array
#pragma unroll
    for (int nt = 0; nt < 2; ++nt) {
      const float u0 = ubuf[0][0][nt][m][nn] + cB2[nt];
      cpr[nt] = cA2[nt] * __cosf(cOm2[nt] * 1.0f + u0);
      unsigned hv = (unsigned)__builtin_bit_cast(unsigned short, (half_t)cpr[nt]);
      const half_t* sp = w0c + off2[nt];
      asm volatile("global_store_short %0, %1, off sc1" :: "v"(sp), "v"(hv) : "memory");
    }
    asm volatile("s_waitcnt vmcnt(0)" ::: "memory");
    if (lane == 0)
      __hip_atomic_store(myf, 1u, __ATOMIC_RELAXED, __HIP_MEMORY_SCOPE_AGENT);
  }
  // x prefetch for round 0: t = 1 + tpar
  float4 xr0, xr1, xr2, xr3;
  {
    const float* xp = x + ((size_t)(1 + tpar) * 64 + b0 + lm) * 64;
    xr0 = *(const float4*)(xp + kg * 8);  xr1 = *(const float4*)(xp + kg * 8 + 4);
    xr2 = *(const float4*)(xp + 32 + kg * 8); xr3 = *(const float4*)(xp + 36 + kg * 8);
  }

  int bR = 0;
  for (int k = 0; k < N_ROUNDS; ++k) {
    const int bW = (bR == 2) ? 0 : bR + 1;
    const half_t* rB = St + (size_t)(bR * 4 + rep) * ST_UNIT;
    half_t* wB       = St + (size_t)(bW * 4 + rep) * ST_UNIT;
    const int par = k & 1;

    // ---- phase A: u for t1=2k+1 (waves 0,1) / t2=2k+2 (waves 2,3)
    {
      f32x4 au = {0.f, 0.f, 0.f, 0.f};
      au = MFMA16(cvt8(xr0, xr1), wi0, au);
      au = MFMA16(cvt8(xr2, xr3), wi1, au);
#pragma unroll
      for (int r = 0; r < 4; ++r) ubuf[par][tpar][ntu][kg * 4 + r][lm] = au[r];
    }

    // ---- phase B: tight-spin poll (agent scope, proven) on 64 producer waves
    {
      const unsigned tgt = (unsigned)(k + 1);
      unsigned v = __hip_atomic_load(pollp, __ATOMIC_RELAXED, __HIP_MEMORY_SCOPE_AGENT);
      while (!__all((int)(v >= tgt)))
        v = __hip_atomic_load(pollp, __ATOMIC_RELAXED, __HIP_MEMORY_SCOPE_AGENT);
    }

    // ---- phase C: load s,c frags of K-slice [512w,+512) from LLC (sc1)
    const half_t* ps0 = rB + (w * 16) * 512 + kg * 128 + lm * 8;
    const half_t* ps1 = ps0 + 2048;
    const half_t* ps2 = ps0 + 4096;
    const half_t* ps3 = ps0 + 6144;
    const half_t* pc0 = ps0 + 32768;
    const half_t* pc1 = ps1 + 32768;
    const half_t* pc2 = ps2 + 32768;
    const half_t* pc3 = ps3 + 32768;
    float4 Sr[16], Cr[16];
    asm volatile(
        "global_load_dwordx4 %0, %32, off sc1\n\t"
        "global_load_dwordx4 %1, %32, off offset:1024 sc1\n\t"
        "global_load_dwordx4 %2, %32, off offset:2048 sc1\n\t"
        "global_load_dwordx4 %3, %32, off offset:3072 sc1\n\t"
        "global_load_dwordx4 %4, %33, off sc1\n\t"
        "global_load_dwordx4 %5, %33, off offset:1024 sc1\n\t"
        "global_load_dwordx4 %6, %33, off offset:2048 sc1\n\t"
        "global_load_dwordx4 %7, %33, off offset:3072 sc1\n\t"
        "global_load_dwordx4 %8, %34, off sc1\n\t"
        "global_load_dwordx4 %9, %34, off offset:1024 sc1\n\t"
        "global_load_dwordx4 %10, %34, off offset:2048 sc1\n\t"
        "global_load_dwordx4 %11, %34, off offset:3072 sc1\n\t"
        "global_load_dwordx4 %12, %35, off sc1\n\t"
        "global_load_dwordx4 %13, %35, off offset:1024 sc1\n\t"
        "global_load_dwordx4 %14, %35, off offset:2048 sc1\n\t"
        "global_load_dwordx4 %15, %35, off offset:3072 sc1\n\t"
        "global_load_dwordx4 %16, %36, off sc1\n\t"
        "global_load_dwordx4 %17, %36, off offset:1024 sc1\n\t"
        "global_load_dwordx4 %18, %36, off offset:2048 sc1\n\t"
        "global_load_dwordx4 %19, %36, off offset:3072 sc1\n\t"
        "global_load_dwordx4 %20, %37, off sc1\n\t"
        "global_load_dwordx4 %21, %37, off offset:1024 sc1\n\t"
        "global_load_dwordx4 %22, %37, off offset:2048 sc1\n\t"
        "global_load_dwordx4 %23, %37, off offset:3072 sc1\n\t"
        "global_load_dwordx4 %24, %38, off sc1\n\t"
        "global_load_dwordx4 %25, %38, off offset:1024 sc1\n\t"
        "global_load_dwordx4 %26, %38, off offset:2048 sc1\n\t"
        "global_load_dwordx4 %27, %38, off offset:3072 sc1\n\t"
        "global_load_dwordx4 %28, %39, off sc1\n\t"
        "global_load_dwordx4 %29, %39, off offset:1024 sc1\n\t"
        "global_load_dwordx4 %30, %39, off offset:2048 sc1\n\t"
        "global_load_dwordx4 %31, %39, off offset:3072 sc1\n\t"
        "s_waitcnt vmcnt(0)"
        : "=&v"(Sr[0]), "=&v"(Sr[1]), "=&v"(Sr[2]), "=&v"(Sr[3]),
          "=&v"(Sr[4]), "=&v"(Sr[5]), "=&v"(Sr[6]), "=&v"(Sr[7]),
          "=&v"(Sr[8]), "=&v"(Sr[9]), "=&v"(Sr[10]), "=&v"(Sr[11]),
          "=&v"(Sr[12]), "=&v"(Sr[13]), "=&v"(Sr[14]), "=&v"(Sr[15]),
          "=&v"(Cr[0]), "=&v"(Cr[1]), "=&v"(Cr[2]), "=&v"(Cr[3]),
          "=&v"(Cr[4]), "=&v"(Cr[5]), "=&v"(Cr[6]), "=&v"(Cr[7]),
          "=&v"(Cr[8]), "=&v"(Cr[9]), "=&v"(Cr[10]), "=&v"(Cr[11]),
          "=&v"(Cr[12]), "=&v"(Cr[13]), "=&v"(Cr[14]), "=&v"(Cr[15])
        : "v"(ps0), "v"(ps1), "v"(ps2), "v"(ps3),
          "v"(pc0), "v"(pc1), "v"(pc2), "v"(pc3)
        : "memory");

    // ---- phase D: y1 = W*s ; y23 = W*c + W^2*s   (96 MFMA)
    f32x4 y1a0 = {0.f,0.f,0.f,0.f}, y1a1 = {0.f,0.f,0.f,0.f};
    f32x4 y23a0 = {0.f,0.f,0.f,0.f}, y23a1 = {0.f,0.f,0.f,0.f};
#pragma unroll
    for (int c = 0; c < 16; ++c) {
      half8 sf = __builtin_bit_cast(half8, Sr[c]);
      half8 cf = __builtin_bit_cast(half8, Cr[c]);
      y1a0 = MFMA16(sf, wb[0][c], y1a0);
      y1a1 = MFMA16(sf, wb[1][c], y1a1);
      y23a0 = MFMA16(cf, wb[0][c], y23a0);
      y23a1 = MFMA16(cf, wb[1][c], y23a1);
      y23a0 = MFMA16(sf, w2b[0][c], y23a0);
      y23a1 = MFMA16(sf, w2b[1][c], y23a1);
    }
#pragma unroll
    for (int r = 0; r < 4; ++r) {
      ybuf[par][w][0][0][kg * 4 + r][lm] = y1a0[r];
      ybuf[par][w][0][1][kg * 4 + r][lm] = y1a1[r];
      ybuf[par][w][1][0][kg * 4 + r][lm] = y23a0[r];
      ybuf[par][w][1][1][kg * 4 + r][lm] = y23a1[r];
    }
    __syncthreads();  // the only barrier per round

    // ---- phase E: combine two steps, publish (s_{2k+2}, c_{2k+2}), flag
#pragma unroll
    for (int nt = 0; nt < 2; ++nt) {
      const float y1v = ybuf[par][0][0][nt][m][nn] + ybuf[par][1][0][nt][m][nn] +
                        ybuf[par][2][0][nt][m][nn] + ybuf[par][3][0][nt][m][nn];
      const float y23v = ybuf[par][0][1][nt][m][nn] + ybuf[par][1][1][nt][m][nn] +
                         ybuf[par][2][1][nt][m][nn] + ybuf[par][3][1][nt][m][nn];
      const float u1 = ubuf[par][0][nt][m][nn] + cB2[nt];
      const float u2 = ubuf[par][1][nt][m][nn] + cB2[nt];
      const float s1 = cpr[nt] + y1v;
      const float c1 = cA2[nt] * __cosf(cOm2[nt] * s1 + u1);
      const float s2 = c1 + y23v;
      const float c2 = cA2[nt] * __cosf(cOm2[nt] * s2 + u2);
      cpr[nt] = c2;
      unsigned hs = (unsigned)__builtin_bit_cast(unsigned short, (half_t)s2);
      unsigned hc = (unsigned)__builtin_bit_cast(unsigned short, (half_t)c2);
      const half_t* sps = wB + off2[nt];
      const half_t* spc = wB + 32768 + off2[nt];
      asm volatile("global_store_short %0, %1, off sc1" :: "v"(sps), "v"(hs) : "memory");
      asm volatile("global_store_short %0, %1, off sc1" :: "v"(spc), "v"(hc) : "memory");
    }
    asm volatile("s_waitcnt vmcnt(0)" ::: "memory");  // wave's stores at LLC
    if (lane == 0)
      __hip_atomic_store(myf, (unsigned)(k + 2), __ATOMIC_RELAXED, __HIP_MEMORY_SCOPE_AGENT);

    // ---- phase G: x prefetch for round k+1 (off the serial chain)
    {
      int t = 2 * k + 3 + tpar;
      if (t > 511) t = 511;  // clamped value feeds an unused c
      const float* xp = x + ((size_t)t * 64 + b0 + lm) * 64;
      xr0 = *(const float4*)(xp + kg * 8);  xr1 = *(const float4*)(xp + kg * 8 + 4);
      xr2 = *(const float4*)(xp + 32 + kg * 8); xr3 = *(const float4*)(xp + 36 + kg * 8);
    }
    bR = bW;
  }
}

__global__ __launch_bounds__(256) void psrnn_readout_kernel(
    const float* __restrict__ Wr_w,   // [64][2048]
    const float* __restrict__ Wr_b,   // [64]
    const half_t* __restrict__ St,    // base of St region
    float* __restrict__ out)          // [64][64]
{
  const int tid = threadIdx.x, v = tid >> 6, lane = tid & 63;
  const int lm = lane & 15, kg = lane >> 4;
  const int rep = blockIdx.x;  // 4 blocks
  // final state s_512 lives in buffer (255+1)%3 = 1, s-array
  const half_t* sb = St + (size_t)(1 * 4 + rep) * ST_UNIT;

  f32x4 acc = {0.f, 0.f, 0.f, 0.f};
  for (int cg = 0; cg < 64; ++cg) {
    half8 a = *(const half8*)(sb + (size_t)cg * 512 + kg * 128 + lm * 8);
    const float* p = Wr_w + (size_t)(v * 16 + lm) * NHID + cg * 32 + kg * 8;
    half8 b = cvt8(*(const float4*)p, *(const float4*)(p + 4));
    acc = MFMA16(a, b, acc);
  }
#pragma unroll
  for (int r = 0; r < 4; ++r) {
    const int bidx = rep * 16 + kg * 4 + r;
    out[bidx * NOUT + v * 16 + lm] = acc[r] + Wr_b[v * 16 + lm];
  }
}

extern "C" void kernel_launch(void* const* d_in, const int* in_sizes, int n_in,
                              void* d_out, int out_size, void* d_ws, size_t ws_size,
                              hipStream_t stream) {
  const float* x    = (const float*)d_in[0];
  const float* Wi_w = (const float*)d_in[1];
  const float* Wi_b = (const float*)d_in[2];
  const float* Wh_w = (const float*)d_in[3];
  const float* Av   = (const float*)d_in[4];
  const float* Om   = (const float*)d_in[5];
  const float* Wr_w = (const float*)d_in[6];
  const float* Wr_b = (const float*)d_in[7];

  unsigned* flags = (unsigned*)d_ws;
  half_t*   St    = (half_t*)((char*)d_ws + 4096);
  half_t*   W2    = (half_t*)((char*)d_ws + (2u << 20));
  half_t*   WT16  = (half_t*)((char*)d_ws + (2u << 20) + (8u << 20));

  psrnn_init_kernel<<<64, 256, 0, stream>>>(flags, (uint4*)St);
  psrnn_transpose_kernel<<<1024, 256, 0, stream>>>(Wh_w, WT16);
  psrnn_w2_kernel<<<1024, 256, 0, stream>>>(Wh_w, WT16, W2);
  psrnn_main_kernel<<<256, 256, 0, stream>>>(x, Wi_w, Wi_b, Wh_w, Av, Om, W2, flags, St);
  psrnn_readout_kernel<<<4, 256, 0, stream>>>(Wr_w, Wr_b, St, (float*)d_out);
}

// Round 7
// 1211.108 us; speedup vs baseline: 1.7503x; 1.0568x over previous
//
#include <hip/hip_runtime.h>

// psRNN round 7: r6 (2 steps/sync via W^2) + dual-path state distribution.
// 4 replicas x 64 blocks x 4 waves; replica r = XCD pair {r, r+4} (roster via
// HW_REG_XCC_ID, r2/r5-proven). Slots 0-31 live on XCD r (half 0), 32-63 on
// XCD r+4 (half 1); +40KB dynamic LDS forces 1 block/CU so the 32-per-XCD
// roster assumption is a HW guarantee. Writers publish (s,c) twice: sc0 (own
// XCD L2) + sc1 (LLC). Reader wave w's 16 producers (slots [16w,+16)) are all
// in half (w>>1): co-XCD waves read the L2 copy (sc0), cross waves read LLC
// (sc1). Halves LLC broadcast 32->16 MB/round; 16 MB served by XCD L2.
// Flags: agent-scope LLC, per-wave, tight spin (r6-proven fast).
// W^2 GEMM v2: 256 blocks, 128x128 tile, B staged in LDS (was ~1.3GB LLC
// traffic / ~180us; now ~380MB / ~45us).

typedef _Float16 half_t;
typedef _Float16 half8 __attribute__((ext_vector_type(8)));
typedef float f32x4 __attribute__((ext_vector_type(4)));

#define NHID 2048
#define NOUT 64
#define ST_UNIT 65536   // halfs per (buf,rep): s [0,32768) + c [32768,65536)
#define N_ROUNDS 256

#define MFMA16(A, B, C) __builtin_amdgcn_mfma_f32_16x16x32_f16(A, B, C, 0, 0, 0)

// ws layout (bytes):
//   [0, 4096)       : flags  uint[4][256]  ([rep][slot*4+wave], monotonic)
//   [4096, 4160)    : roster uint[8]       (per-XCD block counter)
//   [1M, 1M+1.5M)   : StA  half[3][4][ST_UNIT]  (sc0 / XCD-L2 copy)
//   [3M, 3M+1.5M)   : StB  half[3][4][ST_UNIT]  (sc1 / LLC copy)
//   [8M, 16M)       : WT16 half[2048][2048]     (W transposed, f16; dead after w2)
//   [16M, 24M)      : W2   half[2048][2048]

__device__ __forceinline__ half8 cvt8(float4 lo, float4 hi) {
  half8 h;
  h[0] = (half_t)lo.x; h[1] = (half_t)lo.y; h[2] = (half_t)lo.z; h[3] = (half_t)lo.w;
  h[4] = (half_t)hi.x; h[5] = (half_t)hi.y; h[6] = (half_t)hi.z; h[7] = (half_t)hi.w;
  return h;
}

__global__ void psrnn_init_kernel(unsigned* flags, unsigned* roster,
                                  uint4* stA, uint4* stB) {
  int g = blockIdx.x * blockDim.x + threadIdx.x;  // 16384 threads
  uint4 v; v.x = 0x3C003C00u; v.y = 0x3C003C00u; v.z = 0x3C003C00u; v.w = 0x3C003C00u;
  const int rep = g >> 12, local = g & 4095;      // buf0 s := fp16 1.0, both copies
  stA[rep * (ST_UNIT / 8) + local] = v;
  stB[rep * (ST_UNIT / 8) + local] = v;
  if (g < 1024) flags[g] = 0;
  else if (g < 1032) roster[g - 1024] = 0;
}

// W (fp32 row-major) -> WT16 (f16, transposed, row-major)
__global__ __launch_bounds__(256) void psrnn_conv_kernel(
    const float* __restrict__ Wh, half_t* __restrict__ WT16) {
  __shared__ float tile[64][65];
  const int bi = blockIdx.x & 31, bj = blockIdx.x >> 5;
  const int rs = threadIdx.x >> 6, c = threadIdx.x & 63;
#pragma unroll
  for (int i = 0; i < 16; ++i) {
    const int row = rs * 16 + i;
    tile[row][c] = Wh[(size_t)(bi * 64 + row) * NHID + bj * 64 + c];
  }
  __syncthreads();
#pragma unroll
  for (int i = 0; i < 16; ++i) {
    const int row = rs * 16 + i;
    WT16[(size_t)(bj * 64 + row) * NHID + bi * 64 + c] = (half_t)tile[c][row];
  }
}

// W2 = f16( f16(W) @ f16(W) ), 128x128 tiles, B-chunk staged in LDS.
__global__ __launch_bounds__(256) void psrnn_w2_kernel(
    const float* __restrict__ Wh, const half_t* __restrict__ WT16,
    half_t* __restrict__ W2) {
  __shared__ half_t Bs[128][40];  // pad 40: 16B-aligned frags, spread banks
  const int bi = blockIdx.x & 15, bj = blockIdx.x >> 4;
  const int tid = threadIdx.x, w = tid >> 6, lane = tid & 63;
  const int lm = lane & 15, kg = lane >> 4;
  const int brow = tid >> 2, bseg = tid & 3;

  f32x4 acc[2][8];
#pragma unroll
  for (int mt = 0; mt < 2; ++mt)
#pragma unroll
    for (int nt = 0; nt < 8; ++nt) acc[mt][nt] = (f32x4){0.f, 0.f, 0.f, 0.f};

  for (int c = 0; c < 64; ++c) {
    __syncthreads();
#pragma unroll
    for (int i = 0; i < 2; ++i) {
      const int row = brow + i * 64;
      *(half8*)&Bs[row][bseg * 8] =
          *(const half8*)(WT16 + (size_t)(bj * 128 + row) * NHID + c * 32 + bseg * 8);
    }
    __syncthreads();
    const float* pa0 = Wh + (size_t)(bi * 128 + w * 32 + lm) * NHID + c * 32 + kg * 8;
    const float* pa1 = pa0 + (size_t)16 * NHID;
    half8 a0 = cvt8(*(const float4*)pa0, *(const float4*)(pa0 + 4));
    half8 a1 = cvt8(*(const float4*)pa1, *(const float4*)(pa1 + 4));
#pragma unroll
    for (int nt = 0; nt < 8; ++nt) {
      half8 b = *(const half8*)&Bs[nt * 16 + lm][kg * 8];
      acc[0][nt] = MFMA16(a0, b, acc[0][nt]);
      acc[1][nt] = MFMA16(a1, b, acc[1][nt]);
    }
  }
#pragma unroll
  for (int mt = 0; mt < 2; ++mt)
#pragma unroll
    for (int nt = 0; nt < 8; ++nt)
#pragma unroll
      for (int r = 0; r < 4; ++r)
        W2[(size_t)(bi * 128 + w * 32 + mt * 16 + kg * 4 + r) * NHID +
           bj * 128 + nt * 16 + lm] = (half_t)acc[mt][nt][r];
}

__global__ __launch_bounds__(256, 1) void psrnn_main_kernel(
    const float* __restrict__ x,      // [512][64][64]
    const float* __restrict__ Wi_w,   // [2048][64]
    const float* __restrict__ Wi_b,   // [2048]
    const float* __restrict__ Wh_w,   // [2048][2048]
    const float* __restrict__ Av,     // [2048]
    const float* __restrict__ Om,     // [2048]
    const half_t* __restrict__ W2,    // [2048][2048] f16
    unsigned* __restrict__ flags,
    unsigned* __restrict__ roster,
    half_t* __restrict__ StA,         // sc0 / XCD-L2 copy
    half_t* __restrict__ StB)         // sc1 / LLC copy
{
  extern __shared__ char lds_force[];        // +40KB dyn: forces 1 block/CU
  __shared__ float ybuf[2][4][2][2][16][18]; // [par][wave][arr][nt][m][n]
  __shared__ float ubuf[2][2][2][16][18];    // [par][t'][nt][m][n]
  __shared__ unsigned slot_sh;
  (void)lds_force;

  const int tid = threadIdx.x, w = tid >> 6, lane = tid & 63;
  const int lm = lane & 15, kg = lane >> 4;

  unsigned xcd;
  asm volatile("s_getreg_b32 %0, hwreg(HW_REG_XCC_ID)" : "=s"(xcd));
  const int rep    = (int)(xcd & 3u);
  const int halfId = (int)((xcd >> 2) & 1u);
  if (tid == 0) slot_sh = (unsigned)(halfId * 32) + (atomicAdd(&roster[xcd & 7u], 1u) & 31u);
  __syncthreads();
  const int slot = (int)slot_sh;
  const int n0 = slot * 32, b0 = rep * 16;
  const bool locw = ((w >> 1) == halfId);  // my producers are on my XCD
  const int tpar = w >> 1, ntu = w & 1;    // u-duty: wave -> (timestep, nt)

  // ---- W, W2 B-frags: rows n0+16nt+lm, K = 512w + 32c + kg*8..
  half8 wb[2][16], w2b[2][16];
#pragma unroll
  for (int nt = 0; nt < 2; ++nt)
#pragma unroll
    for (int c = 0; c < 16; ++c) {
      const float* p = Wh_w + (size_t)(n0 + nt * 16 + lm) * NHID + (w * 512 + c * 32 + kg * 8);
      wb[nt][c] = cvt8(*(const float4*)p, *(const float4*)(p + 4));
      w2b[nt][c] = *(const half8*)(W2 + (size_t)(n0 + nt * 16 + lm) * NHID +
                                   (w * 512 + c * 32 + kg * 8));
    }
  half8 wi0, wi1;
  {
    const float* p = Wi_w + (size_t)(n0 + ntu * 16 + lm) * 64 + kg * 8;
    wi0 = cvt8(*(const float4*)p, *(const float4*)(p + 4));
    wi1 = cvt8(*(const float4*)(p + 32), *(const float4*)(p + 36));
  }

  // ---- combiner constants: thread owns (batch m, neurons n0+nt*16+nn)
  const int m = tid >> 4, nn = tid & 15;
  float cA2[2], cOm2[2], cB2[2];
  int off2[2];
#pragma unroll
  for (int nt = 0; nt < 2; ++nt) {
    const int ng = n0 + nt * 16 + nn;
    cA2[nt] = Av[ng]; cOm2[nt] = Om[ng]; cB2[nt] = Wi_b[ng];
    off2[nt] = ((slot * 4 + nt * 2 + (nn >> 3)) * 16 + m) * 8 + (nn & 7);
  }
  float cpr[2];

  unsigned* const pollp = flags + rep * 256 + w * 64 + lane;  // 64 producer waves
  unsigned* const myf   = flags + rep * 256 + slot * 4 + w;

  // ---- preloop: u_0 (waves 0,1), publish c_0 to buf0 (both copies), flag=1
  if (w < 2) {
    const float* xp = x + (size_t)(b0 + lm) * 64;
    float4 a0 = *(const float4*)(xp + kg * 8), a1 = *(const float4*)(xp + kg * 8 + 4);
    float4 a2 = *(const float4*)(xp + 32 + kg * 8), a3 = *(const float4*)(xp + 36 + kg * 8);
    f32x4 au = {0.f, 0.f, 0.f, 0.f};
    au = MFMA16(cvt8(a0, a1), wi0, au);
    au = MFMA16(cvt8(a2, a3), wi1, au);
#pragma unroll
    for (int r = 0; r < 4; ++r) ubuf[0][0][ntu][kg * 4 + r][lm] = au[r];
  }
  __syncthreads();
  {
    half_t* cA_ = StA + (size_t)rep * ST_UNIT + 32768;
    half_t* cB_ = StB + (size_t)rep * ST_UNIT + 32768;
#pragma unroll
    for (int nt = 0; nt < 2; ++nt) {
      const float u0 = ubuf[0][0][nt][m][nn] + cB2[nt];
      cpr[nt] = cA2[nt] * __cosf(cOm2[nt] * 1.0f + u0);
      unsigned hv = (unsigned)__builtin_bit_cast(unsigned short, (half_t)cpr[nt]);
      const half_t* pA = cA_ + off2[nt];
      const half_t* pB = cB_ + off2[nt];
      asm volatile("global_store_short %0, %1, off sc0" :: "v"(pA), "v"(hv) : "memory");
      asm volatile("global_store_short %0, %1, off sc1" :: "v"(pB), "v"(hv) : "memory");
    }
    asm volatile("s_waitcnt vmcnt(0)" ::: "memory");
    if (lane == 0)
      __hip_atomic_store(myf, 1u, __ATOMIC_RELAXED, __HIP_MEMORY_SCOPE_AGENT);
  }
  float4 xr0, xr1, xr2, xr3;
  {
    const float* xp = x + ((size_t)(1 + tpar) * 64 + b0 + lm) * 64;
    xr0 = *(const float4*)(xp + kg * 8);  xr1 = *(const float4*)(xp + kg * 8 + 4);
    xr2 = *(const float4*)(xp + 32 + kg * 8); xr3 = *(const float4*)(xp + 36 + kg * 8);
  }

  int bR = 0;
  for (int k = 0; k < N_ROUNDS; ++k) {
    const int bW = (bR == 2) ? 0 : bR + 1;
    const int par = k & 1;

    // ---- phase A: u for t1=2k+1 (waves 0,1) / t2=2k+2 (waves 2,3)
    {
      f32x4 au = {0.f, 0.f, 0.f, 0.f};
      au = MFMA16(cvt8(xr0, xr1), wi0, au);
      au = MFMA16(cvt8(xr2, xr3), wi1, au);
#pragma unroll
      for (int r = 0; r < 4; ++r) ubuf[par][tpar][ntu][kg * 4 + r][lm] = au[r];
    }

    // ---- phase B: tight-spin poll on my 16 producer blocks' 64 wave-flags
    {
      const unsigned tgt = (unsigned)(k + 1);
      unsigned v = __hip_atomic_load(pollp, __ATOMIC_RELAXED, __HIP_MEMORY_SCOPE_AGENT);
      while (!__all((int)(v >= tgt)))
        v = __hip_atomic_load(pollp, __ATOMIC_RELAXED, __HIP_MEMORY_SCOPE_AGENT);
    }

    // ---- phase C: (s,c) frags of K-slice [512w,+512); local half from XCD L2
    //      (sc0, r2/r5-proven), cross half from LLC (sc1, r6-proven)
    const half_t* rb = (locw ? StA : StB) + (size_t)(bR * 4 + rep) * ST_UNIT;
    const half_t* ps0 = rb + w * 8192 + kg * 128 + lm * 8;
    const half_t* ps1 = ps0 + 2048;
    const half_t* ps2 = ps0 + 4096;
    const half_t* ps3 = ps0 + 6144;
    const half_t* pc0 = ps0 + 32768;
    const half_t* pc1 = ps1 + 32768;
    const half_t* pc2 = ps2 + 32768;
    const half_t* pc3 = ps3 + 32768;
    float4 Sr[16], Cr[16];
#define LOADS(SC)                                                         \
    asm volatile(                                                         \
        "global_load_dwordx4 %0, %32, off " SC "\n\t"                     \
        "global_load_dwordx4 %1, %32, off offset:1024 " SC "\n\t"         \
        "global_load_dwordx4 %2, %32, off offset:2048 " SC "\n\t"         \
        "global_load_dwordx4 %3, %32, off offset:3072 " SC "\n\t"         \
        "global_load_dwordx4 %4, %33, off " SC "\n\t"                     \
        "global_load_dwordx4 %5, %33, off offset:1024 " SC "\n\t"         \
        "global_load_dwordx4 %6, %33, off offset:2048 " SC "\n\t"         \
        "global_load_dwordx4 %7, %33, off offset:3072 " SC "\n\t"         \
        "global_load_dwordx4 %8, %34, off " SC "\n\t"                     \
        "global_load_dwordx4 %9, %34, off offset:1024 " SC "\n\t"         \
        "global_load_dwordx4 %10, %34, off offset:2048 " SC "\n\t"        \
        "global_load_dwordx4 %11, %34, off offset:3072 " SC "\n\t"        \
        "global_load_dwordx4 %12, %35, off " SC "\n\t"                    \
        "global_load_dwordx4 %13, %35, off offset:1024 " SC "\n\t"        \
        "global_load_dwordx4 %14, %35, off offset:2048 " SC "\n\t"        \
        "global_load_dwordx4 %15, %35, off offset:3072 " SC "\n\t"        \
        "global_load_dwordx4 %16, %36, off " SC "\n\t"                    \
        "global_load_dwordx4 %17, %36, off offset:1024 " SC "\n\t"        \
        "global_load_dwordx4 %18, %36, off offset:2048 " SC "\n\t"        \
        "global_load_dwordx4 %19, %36, off offset:3072 " SC "\n\t"        \
        "global_load_dwordx4 %20, %37, off " SC "\n\t"                    \
        "global_load_dwordx4 %21, %37, off offset:1024 " SC "\n\t"        \
        "global_load_dwordx4 %22, %37, off offset:2048 " SC "\n\t"        \
        "global_load_dwordx4 %23, %37, off offset:3072 " SC "\n\t"        \
        "global_load_dwordx4 %24, %38, off " SC "\n\t"                    \
        "global_load_dwordx4 %25, %38, off offset:1024 " SC "\n\t"        \
        "global_load_dwordx4 %26, %38, off offset:2048 " SC "\n\t"        \
        "global_load_dwordx4 %27, %38, off offset:3072 " SC "\n\t"        \
        "global_load_dwordx4 %28, %39, off " SC "\n\t"                    \
        "global_load_dwordx4 %29, %39, off offset:1024 " SC "\n\t"        \
        "global_load_dwordx4 %30, %39, off offset:2048 " SC "\n\t"        \
        "global_load_dwordx4 %31, %39, off offset:3072 " SC "\n\t"        \
        "s_waitcnt vmcnt(0)"                                              \
        : "=&v"(Sr[0]), "=&v"(Sr[1]), "=&v"(Sr[2]), "=&v"(Sr[3]),         \
          "=&v"(Sr[4]), "=&v"(Sr[5]), "=&v"(Sr[6]), "=&v"(Sr[7]),         \
          "=&v"(Sr[8]), "=&v"(Sr[9]), "=&v"(Sr[10]), "=&v"(Sr[11]),       \
          "=&v"(Sr[12]), "=&v"(Sr[13]), "=&v"(Sr[14]), "=&v"(Sr[15]),     \
          "=&v"(Cr[0]), "=&v"(Cr[1]), "=&v"(Cr[2]), "=&v"(Cr[3]),         \
          "=&v"(Cr[4]), "=&v"(Cr[5]), "=&v"(Cr[6]), "=&v"(Cr[7]),         \
          "=&v"(Cr[8]), "=&v"(Cr[9]), "=&v"(Cr[10]), "=&v"(Cr[11]),       \
          "=&v"(Cr[12]), "=&v"(Cr[13]), "=&v"(Cr[14]), "=&v"(Cr[15])      \
        : "v"(ps0), "v"(ps1), "v"(ps2), "v"(ps3),                         \
          "v"(pc0), "v"(pc1), "v"(pc2), "v"(pc3)                          \
        : "memory")
    if (locw) { LOADS("sc0"); } else { LOADS("sc1"); }
#undef LOADS

    // ---- phase D: y1 = W*s ; y23 = W*c + W^2*s   (96 MFMA)
    f32x4 y1a0 = {0.f,0.f,0.f,0.f}, y1a1 = {0.f,0.f,0.f,0.f};
    f32x4 y23a0 = {0.f,0.f,0.f,0.f}, y23a1 = {0.f,0.f,0.f,0.f};
#pragma unroll
    for (int c = 0; c < 16; ++c) {
      half8 sf = __builtin_bit_cast(half8, Sr[c]);
      half8 cf = __builtin_bit_cast(half8, Cr[c]);
      y1a0 = MFMA16(sf, wb[0][c], y1a0);
      y1a1 = MFMA16(sf, wb[1][c], y1a1);
      y23a0 = MFMA16(cf, wb[0][c], y23a0);
      y23a1 = MFMA16(cf, wb[1][c], y23a1);
      y23a0 = MFMA16(sf, w2b[0][c], y23a0);
      y23a1 = MFMA16(sf, w2b[1][c], y23a1);
    }
#pragma unroll
    for (int r = 0; r < 4; ++r) {
      ybuf[par][w][0][0][kg * 4 + r][lm] = y1a0[r];
      ybuf[par][w][0][1][kg * 4 + r][lm] = y1a1[r];
      ybuf[par][w][1][0][kg * 4 + r][lm] = y23a0[r];
      ybuf[par][w][1][1][kg * 4 + r][lm] = y23a1[r];
    }
    __syncthreads();  // the only barrier per round

    // ---- phase E: combine two steps, dual-publish (s,c), flag
    half_t* wBA = StA + (size_t)(bW * 4 + rep) * ST_UNIT;
    half_t* wBB = StB + (size_t)(bW * 4 + rep) * ST_UNIT;
#pragma unroll
    for (int nt = 0; nt < 2; ++nt) {
      const float y1v = ybuf[par][0][0][nt][m][nn] + ybuf[par][1][0][nt][m][nn] +
                        ybuf[par][2][0][nt][m][nn] + ybuf[par][3][0][nt][m][nn];
      const float y23v = ybuf[par][0][1][nt][m][nn] + ybuf[par][1][1][nt][m][nn] +
                         ybuf[par][2][1][nt][m][nn] + ybuf[par][3][1][nt][m][nn];
      const float u1 = ubuf[par][0][nt][m][nn] + cB2[nt];
      const float u2 = ubuf[par][1][nt][m][nn] + cB2[nt];
      const float s1 = cpr[nt] + y1v;
      const float c1 = cA2[nt] * __cosf(cOm2[nt] * s1 + u1);
      const float s2 = c1 + y23v;
      const float c2 = cA2[nt] * __cosf(cOm2[nt] * s2 + u2);
      cpr[nt] = c2;
      unsigned hs = (unsigned)__builtin_bit_cast(unsigned short, (half_t)s2);
      unsigned hc = (unsigned)__builtin_bit_cast(unsigned short, (half_t)c2);
      const half_t* sA = wBA + off2[nt];
      const half_t* sB = wBB + off2[nt];
      const half_t* cAp = wBA + 32768 + off2[nt];
      const half_t* cBp = wBB + 32768 + off2[nt];
      asm volatile("global_store_short %0, %1, off sc0" :: "v"(sA), "v"(hs) : "memory");
      asm volatile("global_store_short %0, %1, off sc1" :: "v"(sB), "v"(hs) : "memory");
      asm volatile("global_store_short %0, %1, off sc0" :: "v"(cAp), "v"(hc) : "memory");
      asm volatile("global_store_short %0, %1, off sc1" :: "v"(cBp), "v"(hc) : "memory");
    }
    asm volatile("s_waitcnt vmcnt(0)" ::: "memory");
    if (lane == 0)
      __hip_atomic_store(myf, (unsigned)(k + 2), __ATOMIC_RELAXED, __HIP_MEMORY_SCOPE_AGENT);

    // ---- phase G: x prefetch for round k+1 (off the serial chain)
    {
      int t = 2 * k + 3 + tpar;
      if (t > 511) t = 511;
      const float* xp = x + ((size_t)t * 64 + b0 + lm) * 64;
      xr0 = *(const float4*)(xp + kg * 8);  xr1 = *(const float4*)(xp + kg * 8 + 4);
      xr2 = *(const float4*)(xp + 32 + kg * 8); xr3 = *(const float4*)(xp + 36 + kg * 8);
    }
    bR = bW;
  }
}

__global__ __launch_bounds__(256) void psrnn_readout_kernel(
    const float* __restrict__ Wr_w,   // [64][2048]
    const float* __restrict__ Wr_b,   // [64]
    const half_t* __restrict__ StB,   // LLC copy; final state in buf 1
    float* __restrict__ out)          // [64][64]
{
  const int tid = threadIdx.x, v = tid >> 6, lane = tid & 63;
  const int lm = lane & 15, kg = lane >> 4;
  const int rep = blockIdx.x;  // 4 blocks
  const half_t* sb = StB + (size_t)(1 * 4 + rep) * ST_UNIT;  // buf (255+1)%3 = 1

  f32x4 acc = {0.f, 0.f, 0.f, 0.f};
  for (int cg = 0; cg < 64; ++cg) {
    half8 a = *(const half8*)(sb + (size_t)cg * 512 + kg * 128 + lm * 8);
    const float* p = Wr_w + (size_t)(v * 16 + lm) * NHID + cg * 32 + kg * 8;
    half8 b = cvt8(*(const float4*)p, *(const float4*)(p + 4));
    acc = MFMA16(a, b, acc);
  }
#pragma unroll
  for (int r = 0; r < 4; ++r) {
    const int bidx = rep * 16 + kg * 4 + r;
    out[bidx * NOUT + v * 16 + lm] = acc[r] + Wr_b[v * 16 + lm];
  }
}

extern "C" void kernel_launch(void* const* d_in, const int* in_sizes, int n_in,
                              void* d_out, int out_size, void* d_ws, size_t ws_size,
                              hipStream_t stream) {
  const float* x    = (const float*)d_in[0];
  const float* Wi_w = (const float*)d_in[1];
  const float* Wi_b = (const float*)d_in[2];
  const float* Wh_w = (const float*)d_in[3];
  const float* Av   = (const float*)d_in[4];
  const float* Om   = (const float*)d_in[5];
  const float* Wr_w = (const float*)d_in[6];
  const float* Wr_b = (const float*)d_in[7];

  unsigned* flags  = (unsigned*)d_ws;
  unsigned* roster = (unsigned*)((char*)d_ws + 4096);
  half_t*   StA    = (half_t*)((char*)d_ws + (1u << 20));
  half_t*   StB    = (half_t*)((char*)d_ws + (3u << 20));
  half_t*   WT16   = (half_t*)((char*)d_ws + (8u << 20));
  half_t*   W2     = (half_t*)((char*)d_ws + (16u << 20));

  psrnn_conv_kernel<<<1024, 256, 0, stream>>>(Wh_w, WT16);
  psrnn_w2_kernel<<<256, 256, 0, stream>>>(Wh_w, WT16, W2);
  psrnn_init_kernel<<<64, 256, 0, stream>>>(flags, roster, (uint4*)StA, (uint4*)StB);
  psrnn_main_kernel<<<256, 256, 40960, stream>>>(x, Wi_w, Wi_b, Wh_w, Av, Om, W2,
                                                 flags, roster, StA, StB);
  psrnn_readout_kernel<<<4, 256, 0, stream>>>(Wr_w, Wr_b, StB, (float*)d_out);
}